// Round 1
// baseline (1156.824 us; speedup 1.0000x reference)
//
#include <hip/hip_runtime.h>

#define DIMS 128

// ---------------- CSR build ----------------

__global__ void hist_kernel(const int* __restrict__ row, int E, int* __restrict__ ofs) {
    int idx = blockIdx.x * blockDim.x + threadIdx.x;
    int stride = gridDim.x * blockDim.x;
    for (int e = idx; e < E; e += stride) atomicAdd(&ofs[row[e]], 1);
}

__global__ void tile_sum_kernel(const int* __restrict__ ofs, int N, int* __restrict__ bsum) {
    __shared__ int s[256];
    int i = blockIdx.x * 256 + threadIdx.x;
    s[threadIdx.x] = (i < N) ? ofs[i] : 0;
    __syncthreads();
    for (int d = 128; d > 0; d >>= 1) {
        if (threadIdx.x < (unsigned)d) s[threadIdx.x] += s[threadIdx.x + d];
        __syncthreads();
    }
    if (threadIdx.x == 0) bsum[blockIdx.x] = s[0];
}

// single block, exclusive scan of nb (<=1024) block sums in place
__global__ void scan_bsum_kernel(int* bsum, int nb) {
    __shared__ int s[1024];
    int v = (threadIdx.x < (unsigned)nb) ? bsum[threadIdx.x] : 0;
    s[threadIdx.x] = v;
    __syncthreads();
    for (int d = 1; d < 1024; d <<= 1) {
        int t = 0;
        if (threadIdx.x >= (unsigned)d) t = s[threadIdx.x - d];
        __syncthreads();
        s[threadIdx.x] += t;
        __syncthreads();
    }
    if (threadIdx.x < (unsigned)nb) bsum[threadIdx.x] = s[threadIdx.x] - v;  // exclusive
}

__global__ void tile_scan_kernel(int* ofs, int N, const int* __restrict__ bsum) {
    __shared__ int s[256];
    int i = blockIdx.x * 256 + threadIdx.x;
    int v = (i < N) ? ofs[i] : 0;
    s[threadIdx.x] = v;
    __syncthreads();
    for (int d = 1; d < 256; d <<= 1) {
        int t = 0;
        if (threadIdx.x >= (unsigned)d) t = s[threadIdx.x - d];
        __syncthreads();
        s[threadIdx.x] += t;
        __syncthreads();
    }
    if (i < N) ofs[i] = s[threadIdx.x] - v + bsum[blockIdx.x];  // exclusive global offset
}

// counting-sort scatter; mutates ofs so afterwards ofs[r] == inclusive end of row r
__global__ void scatter_kernel(const int* __restrict__ row, const int* __restrict__ col,
                               const float* __restrict__ val, int E,
                               int* __restrict__ ofs, int* __restrict__ col_s,
                               float* __restrict__ val_s) {
    int idx = blockIdx.x * blockDim.x + threadIdx.x;
    int stride = gridDim.x * blockDim.x;
    for (int e = idx; e < E; e += stride) {
        int r = row[e];
        int p = atomicAdd(&ofs[r], 1);
        col_s[p] = col[e];
        val_s[p] = val[e];
    }
}

// ---------------- SpMM: one wave (64 lanes) per row, float2/lane = 128 dims ----------------
// MODE 0: emb_out = A*emb_in; acc = x + emb_out          (layer 1, acc==d_out)
// MODE 1: emb_out = A*emb_in; acc += emb_out             (layer 2)
// MODE 2: acc = (acc + A*emb_in) * 0.25                  (layer 3, final)
template <int MODE>
__global__ __launch_bounds__(256) void spmm_kernel(
    const float* __restrict__ emb_in, const int* __restrict__ ofs_end,
    const int* __restrict__ col_s, const float* __restrict__ val_s, int N,
    float* __restrict__ emb_out, float* __restrict__ acc, const float* __restrict__ x) {
    int r = (blockIdx.x * blockDim.x + threadIdx.x) >> 6;  // wave id = row
    int lane = threadIdx.x & 63;
    if (r >= N) return;
    int start = (r > 0) ? ofs_end[r - 1] : 0;
    int end = ofs_end[r];
    const int di = lane * 2;

    float2 a0 = make_float2(0.f, 0.f), a1 = make_float2(0.f, 0.f);
    int e = start;
    for (; e + 1 < end; e += 2) {  // 2-way unroll: two gathers in flight
        int c0 = col_s[e], c1 = col_s[e + 1];
        float v0 = val_s[e], v1 = val_s[e + 1];
        float2 t0 = *reinterpret_cast<const float2*>(&emb_in[(size_t)c0 * DIMS + di]);
        float2 t1 = *reinterpret_cast<const float2*>(&emb_in[(size_t)c1 * DIMS + di]);
        a0.x += v0 * t0.x; a0.y += v0 * t0.y;
        a1.x += v1 * t1.x; a1.y += v1 * t1.y;
    }
    if (e < end) {
        int c0 = col_s[e];
        float v0 = val_s[e];
        float2 t0 = *reinterpret_cast<const float2*>(&emb_in[(size_t)c0 * DIMS + di]);
        a0.x += v0 * t0.x; a0.y += v0 * t0.y;
    }
    float2 a = make_float2(a0.x + a1.x, a0.y + a1.y);

    size_t o = (size_t)r * DIMS + di;
    if (MODE == 0) {
        *reinterpret_cast<float2*>(&emb_out[o]) = a;
        float2 xv = *reinterpret_cast<const float2*>(&x[o]);
        *reinterpret_cast<float2*>(&acc[o]) = make_float2(xv.x + a.x, xv.y + a.y);
    } else if (MODE == 1) {
        *reinterpret_cast<float2*>(&emb_out[o]) = a;
        float2 cv = *reinterpret_cast<float2*>(&acc[o]);
        *reinterpret_cast<float2*>(&acc[o]) = make_float2(cv.x + a.x, cv.y + a.y);
    } else {
        float2 cv = *reinterpret_cast<float2*>(&acc[o]);
        *reinterpret_cast<float2*>(&acc[o]) =
            make_float2((cv.x + a.x) * 0.25f, (cv.y + a.y) * 0.25f);
    }
}

// ---------------- launch ----------------

extern "C" void kernel_launch(void* const* d_in, const int* in_sizes, int n_in,
                              void* d_out, int out_size, void* d_ws, size_t ws_size,
                              hipStream_t stream) {
    const float* x = (const float*)d_in[0];
    const int* erow = (const int*)d_in[1];
    const int* ecol = (const int*)d_in[2];
    const float* eval = (const float*)d_in[3];
    const int N = in_sizes[0] / DIMS;   // 100000
    const int E = in_sizes[1];          // 3200000
    float* out = (float*)d_out;

    // workspace carve-up (256B aligned)
    char* ws = (char*)d_ws;
    size_t off = 0;
    auto carve = [&](size_t bytes) {
        void* p = ws + off;
        off = (off + bytes + 255) & ~(size_t)255;
        return p;
    };
    float* embB1 = (float*)carve((size_t)N * DIMS * sizeof(float));
    float* embB2 = (float*)carve((size_t)N * DIMS * sizeof(float));
    int* col_s = (int*)carve((size_t)E * sizeof(int));
    float* val_s = (float*)carve((size_t)E * sizeof(float));
    int* ofs = (int*)carve((size_t)N * sizeof(int));
    const int nb = (N + 255) / 256;     // 391 <= 1024
    int* bsum = (int*)carve((size_t)nb * sizeof(int));
    (void)ws_size;

    // --- build CSR (once, reused by all 3 layers) ---
    hipMemsetAsync(ofs, 0, (size_t)N * sizeof(int), stream);
    hist_kernel<<<2048, 256, 0, stream>>>(erow, E, ofs);
    tile_sum_kernel<<<nb, 256, 0, stream>>>(ofs, N, bsum);
    scan_bsum_kernel<<<1, 1024, 0, stream>>>(bsum, nb);
    tile_scan_kernel<<<nb, 256, 0, stream>>>(ofs, N, bsum);
    scatter_kernel<<<2048, 256, 0, stream>>>(erow, ecol, eval, E, ofs, col_s, val_s);

    // --- 3 layers, one wave per row ---
    const int spmm_blocks = (N + 3) / 4;  // 4 waves (rows) per 256-thread block
    spmm_kernel<0><<<spmm_blocks, 256, 0, stream>>>(x, ofs, col_s, val_s, N, embB1, out, x);
    spmm_kernel<1><<<spmm_blocks, 256, 0, stream>>>(embB1, ofs, col_s, val_s, N, embB2, out, x);
    spmm_kernel<2><<<spmm_blocks, 256, 0, stream>>>(embB2, ofs, col_s, val_s, N, embB1, out, x);
}

// Round 2
// 921.041 us; speedup vs baseline: 1.2560x; 1.2560x over previous
//
#include <hip/hip_runtime.h>

#define DIMS 128

typedef _Float16 half_t;
typedef _Float16 half2_t __attribute__((ext_vector_type(2)));

// ---------------- CSR build ----------------

__global__ void hist_kernel(const int* __restrict__ row, int E, int* __restrict__ ofs) {
    int idx = blockIdx.x * blockDim.x + threadIdx.x;
    int stride = gridDim.x * blockDim.x;
    for (int e = idx; e < E; e += stride) atomicAdd(&ofs[row[e]], 1);
}

__global__ void tile_sum_kernel(const int* __restrict__ ofs, int N, int* __restrict__ bsum) {
    __shared__ int s[256];
    int i = blockIdx.x * 256 + threadIdx.x;
    s[threadIdx.x] = (i < N) ? ofs[i] : 0;
    __syncthreads();
    for (int d = 128; d > 0; d >>= 1) {
        if (threadIdx.x < (unsigned)d) s[threadIdx.x] += s[threadIdx.x + d];
        __syncthreads();
    }
    if (threadIdx.x == 0) bsum[blockIdx.x] = s[0];
}

// single block, exclusive scan of nb (<=1024) block sums in place
__global__ void scan_bsum_kernel(int* bsum, int nb) {
    __shared__ int s[1024];
    int v = (threadIdx.x < (unsigned)nb) ? bsum[threadIdx.x] : 0;
    s[threadIdx.x] = v;
    __syncthreads();
    for (int d = 1; d < 1024; d <<= 1) {
        int t = 0;
        if (threadIdx.x >= (unsigned)d) t = s[threadIdx.x - d];
        __syncthreads();
        s[threadIdx.x] += t;
        __syncthreads();
    }
    if (threadIdx.x < (unsigned)nb) bsum[threadIdx.x] = s[threadIdx.x] - v;  // exclusive
}

__global__ void tile_scan_kernel(int* ofs, int N, const int* __restrict__ bsum) {
    __shared__ int s[256];
    int i = blockIdx.x * 256 + threadIdx.x;
    int v = (i < N) ? ofs[i] : 0;
    s[threadIdx.x] = v;
    __syncthreads();
    for (int d = 1; d < 256; d <<= 1) {
        int t = 0;
        if (threadIdx.x >= (unsigned)d) t = s[threadIdx.x - d];
        __syncthreads();
        s[threadIdx.x] += t;
        __syncthreads();
    }
    if (i < N) ofs[i] = s[threadIdx.x] - v + bsum[blockIdx.x];  // exclusive global offset
}

// counting-sort scatter of packed (col, val) int2; mutates ofs so afterwards
// ofs[r] == inclusive end of row r
__global__ void scatter_kernel(const int* __restrict__ row, const int* __restrict__ col,
                               const float* __restrict__ val, int E,
                               int* __restrict__ ofs, int2* __restrict__ edges) {
    int idx = blockIdx.x * blockDim.x + threadIdx.x;
    int stride = gridDim.x * blockDim.x;
    for (int e = idx; e < E; e += stride) {
        int r = row[e];
        int p = atomicAdd(&ofs[r], 1);
        int2 pk;
        pk.x = col[e];
        pk.y = __float_as_int(val[e]);
        edges[p] = pk;
    }
}

// fp32 -> fp16 convert (x -> xh), 2 elems/thread
__global__ void cvt_kernel(const float* __restrict__ src, half_t* __restrict__ dst, int n2) {
    int i = blockIdx.x * blockDim.x + threadIdx.x;
    if (i >= n2) return;
    float2 v = reinterpret_cast<const float2*>(src)[i];
    half2_t h;
    h.x = (half_t)v.x;
    h.y = (half_t)v.y;
    reinterpret_cast<half2_t*>(dst)[i] = h;
}

// ---------------- SpMM: one wave (64 lanes) per row, half2/lane = 128 dims ----------------
// MODE 0: emb_out = A*emb_in (fp16); acc = x + A*emb_in   (layer 1, acc==d_out)
// MODE 1: emb_out = A*emb_in (fp16); acc += A*emb_in      (layer 2)
// MODE 2: acc = (acc + A*emb_in) * 0.25                   (layer 3, final, fp32 only)
template <int MODE>
__global__ __launch_bounds__(256) void spmm_kernel(
    const half_t* __restrict__ emb_in, const int* __restrict__ ofs_end,
    const int2* __restrict__ edges, int N,
    half_t* __restrict__ emb_out, float* __restrict__ acc, const float* __restrict__ x) {
    int r = (blockIdx.x * blockDim.x + threadIdx.x) >> 6;  // wave id = row
    int lane = threadIdx.x & 63;
    if (r >= N) return;
    int start = (r > 0) ? ofs_end[r - 1] : 0;
    int end = ofs_end[r];
    const int di = lane * 2;

    float ax0 = 0.f, ay0 = 0.f, ax1 = 0.f, ay1 = 0.f;
    float ax2 = 0.f, ay2 = 0.f, ax3 = 0.f, ay3 = 0.f;
    int e = start;
    for (; e + 3 < end; e += 4) {  // 4-way unroll: four gathers in flight
        int2 p0 = edges[e], p1 = edges[e + 1], p2 = edges[e + 2], p3 = edges[e + 3];
        half2_t t0 = *reinterpret_cast<const half2_t*>(&emb_in[(size_t)p0.x * DIMS + di]);
        half2_t t1 = *reinterpret_cast<const half2_t*>(&emb_in[(size_t)p1.x * DIMS + di]);
        half2_t t2 = *reinterpret_cast<const half2_t*>(&emb_in[(size_t)p2.x * DIMS + di]);
        half2_t t3 = *reinterpret_cast<const half2_t*>(&emb_in[(size_t)p3.x * DIMS + di]);
        float v0 = __int_as_float(p0.y), v1 = __int_as_float(p1.y);
        float v2 = __int_as_float(p2.y), v3 = __int_as_float(p3.y);
        ax0 += v0 * (float)t0.x; ay0 += v0 * (float)t0.y;
        ax1 += v1 * (float)t1.x; ay1 += v1 * (float)t1.y;
        ax2 += v2 * (float)t2.x; ay2 += v2 * (float)t2.y;
        ax3 += v3 * (float)t3.x; ay3 += v3 * (float)t3.y;
    }
    for (; e < end; ++e) {
        int2 p0 = edges[e];
        half2_t t0 = *reinterpret_cast<const half2_t*>(&emb_in[(size_t)p0.x * DIMS + di]);
        float v0 = __int_as_float(p0.y);
        ax0 += v0 * (float)t0.x; ay0 += v0 * (float)t0.y;
    }
    float ax = (ax0 + ax1) + (ax2 + ax3);
    float ay = (ay0 + ay1) + (ay2 + ay3);

    size_t o = (size_t)r * DIMS + di;
    if (MODE == 0 || MODE == 1) {
        half2_t h;
        h.x = (half_t)ax;
        h.y = (half_t)ay;
        *reinterpret_cast<half2_t*>(&emb_out[o]) = h;
    }
    if (MODE == 0) {
        float2 xv = *reinterpret_cast<const float2*>(&x[o]);
        *reinterpret_cast<float2*>(&acc[o]) = make_float2(xv.x + ax, xv.y + ay);
    } else if (MODE == 1) {
        float2 cv = *reinterpret_cast<float2*>(&acc[o]);
        *reinterpret_cast<float2*>(&acc[o]) = make_float2(cv.x + ax, cv.y + ay);
    } else {
        float2 cv = *reinterpret_cast<float2*>(&acc[o]);
        *reinterpret_cast<float2*>(&acc[o]) =
            make_float2((cv.x + ax) * 0.25f, (cv.y + ay) * 0.25f);
    }
}

// ---------------- launch ----------------

extern "C" void kernel_launch(void* const* d_in, const int* in_sizes, int n_in,
                              void* d_out, int out_size, void* d_ws, size_t ws_size,
                              hipStream_t stream) {
    const float* x = (const float*)d_in[0];
    const int* erow = (const int*)d_in[1];
    const int* ecol = (const int*)d_in[2];
    const float* eval = (const float*)d_in[3];
    const int N = in_sizes[0] / DIMS;   // 100000
    const int E = in_sizes[1];          // 3200000
    float* out = (float*)d_out;

    // workspace carve-up (256B aligned)
    char* ws = (char*)d_ws;
    size_t off = 0;
    auto carve = [&](size_t bytes) {
        void* p = ws + off;
        off = (off + bytes + 255) & ~(size_t)255;
        return p;
    };
    half_t* xh = (half_t*)carve((size_t)N * DIMS * sizeof(half_t));
    half_t* embB1 = (half_t*)carve((size_t)N * DIMS * sizeof(half_t));
    half_t* embB2 = (half_t*)carve((size_t)N * DIMS * sizeof(half_t));
    int2* edges = (int2*)carve((size_t)E * sizeof(int2));
    int* ofs = (int*)carve((size_t)N * sizeof(int));
    const int nb = (N + 255) / 256;     // 391 <= 1024
    int* bsum = (int*)carve((size_t)nb * sizeof(int));
    (void)ws_size;

    // --- build CSR (once, reused by all 3 layers) + fp16 copy of x ---
    hipMemsetAsync(ofs, 0, (size_t)N * sizeof(int), stream);
    const int n2 = N * DIMS / 2;
    cvt_kernel<<<(n2 + 255) / 256, 256, 0, stream>>>(x, xh, n2);
    hist_kernel<<<2048, 256, 0, stream>>>(erow, E, ofs);
    tile_sum_kernel<<<nb, 256, 0, stream>>>(ofs, N, bsum);
    scan_bsum_kernel<<<1, 1024, 0, stream>>>(bsum, nb);
    tile_scan_kernel<<<nb, 256, 0, stream>>>(ofs, N, bsum);
    scatter_kernel<<<2048, 256, 0, stream>>>(erow, ecol, eval, E, ofs, edges);

    // --- 3 layers, one wave per row ---
    const int spmm_blocks = (N + 3) / 4;  // 4 waves (rows) per 256-thread block
    spmm_kernel<0><<<spmm_blocks, 256, 0, stream>>>(xh, ofs, edges, N, embB1, out, x);
    spmm_kernel<1><<<spmm_blocks, 256, 0, stream>>>(embB1, ofs, edges, N, embB2, out, x);
    spmm_kernel<2><<<spmm_blocks, 256, 0, stream>>>(embB2, ofs, edges, N, embB1, out, x);
}